// Round 3
// baseline (161.467 us; speedup 1.0000x reference)
//
#include <hip/hip_runtime.h>
#include <math.h>

#define BSZ 65536
#define NC 10
#define T 8
#define NE 128
#define EMB 256
#define ZD 128
#define NCT 80
#define CCF 0.25f
#define BB 32

// ws float offsets
#define WT_OFF  0        // Wt[80][128] fp32, k-major (W[d][k] = Wt[k*128+d])
#define B2_OFF  10240    // 128 fused bias
#define BH_OFF  10368    // 4096 halves: MFMA1 B-frags (neg-codebook hi + cn/2 hi)
#define BL_OFF  12416    // 4096 halves: MFMA2 B-frags (lo parts)
#define CT_OFF  14464    // 128 u32 histogram
#define SQ_OFF  14592    // 1 float sq-err accumulator
#define G_OFF   16384    // G[8][128][128] fp32 gather table (512 KB)

typedef _Float16 half8 __attribute__((ext_vector_type(8)));
typedef float f32x4 __attribute__((ext_vector_type(4)));

// ---------------------------------------------------------------------------
// prep1: Wt = (mu_w@fc_w)^T fp32; b2 = mu_w@fc_b + mu_b; B-frag tables for the
// VQ distance MFMA (split-f16 negated codebook, cn/2 injected at k=10/26).
// ---------------------------------------------------------------------------
__global__ __launch_bounds__(256) void prep1_kernel(
    const float* __restrict__ codebook, const float* __restrict__ fc_w,
    const float* __restrict__ fc_b, const float* __restrict__ mu_w,
    const float* __restrict__ mu_b, float* __restrict__ ws)
{
  const int blk = blockIdx.x, tid = threadIdx.x;
  if (blk < 80) {                       // 80*256/2 = 10240 W elements
    const int gi = blk * 256 + tid;
    const int idx = gi >> 1, h = gi & 1;
    const int d = idx / NCT, k = idx - d * NCT;
    const float* mw = mu_w + d * EMB + h * 128;
    const float* fw = fc_w + (h * 128) * NCT + k;
    float acc = 0.f;
#pragma unroll 8
    for (int e = 0; e < 128; ++e) acc = fmaf(mw[e], fw[e * NCT], acc);
    acc += __shfl_xor(acc, 1);
    if (h == 0) ws[WT_OFF + k * 128 + d] = acc;
  } else if (blk == 80) {               // b2
    const int d = tid >> 1, h = tid & 1;
    const float* mw = mu_w + d * EMB + h * 128;
    const float* fb = fc_b + h * 128;
    float acc = 0.f;
#pragma unroll 8
    for (int e = 0; e < 128; ++e) acc = fmaf(mw[e], fb[e], acc);
    acc += __shfl_xor(acc, 1);
    if (h == 0) ws[B2_OFF + d] = acc + mu_b[d];
  } else {                              // blk 81: nt 0..3, blk 82: nt 4..7
    const int nt = (blk - 81) * 4 + (tid >> 6);
    const int lane = tid & 63;
    const int rl = lane & 15, q = lane >> 4;
    const int e = nt * 16 + rl;
    float cb_[NC];
    float cn = 0.f;
#pragma unroll
    for (int c = 0; c < NC; ++c) { cb_[c] = codebook[e * NC + c]; cn = fmaf(cb_[c], cb_[c], cn); }
    const float cn2 = 0.5f * cn;
    half8 hv, lv;
#pragma unroll
    for (int j = 0; j < 8; ++j) {
      const int k = q * 8 + j;
      float hh = 0.f, ll = 0.f;
      if (k < 10) {
        float m = -cb_[k];
        float mh = (float)(_Float16)m;
        hh = mh; ll = m - mh;
      } else if (k == 10) {
        hh = (float)(_Float16)cn2;           // cn/2 hi -> BH (pairs with A=1)
      } else if (k >= 16 && k < 26) {
        float m = -cb_[k - 16];
        float mh = (float)(_Float16)m;
        hh = mh; ll = m - mh;
      } else if (k == 26) {
        ll = cn2 - (float)(_Float16)cn2;     // cn/2 lo -> BL (pairs with A=1)
        hh = 0.f;
      }
      hv[j] = (_Float16)hh; lv[j] = (_Float16)ll;
    }
    ((half8*)((char*)ws + BH_OFF * 4))[nt * 64 + lane] = hv;
    ((half8*)((char*)ws + BL_OFF * 4))[nt * 64 + lane] = lv;
    if (blk == 82) {
      if (tid < NE) ((unsigned*)ws)[CT_OFF + tid] = 0u;
      if (tid == 0) ws[SQ_OFF] = 0.f;
    }
  }
}

// ---------------------------------------------------------------------------
// prep2: G[t][e][d] = sum_c cb[e][c] * W[d][c*8+t]   (needs Wt complete)
// ---------------------------------------------------------------------------
__global__ __launch_bounds__(128) void prep2_kernel(
    const float* __restrict__ codebook, float* __restrict__ ws)
{
  const int t = blockIdx.x >> 7, e = blockIdx.x & 127, d = threadIdx.x;
  float acc = 0.f;
#pragma unroll
  for (int c = 0; c < NC; ++c)
    acc = fmaf(codebook[e * NC + c], ws[WT_OFF + (c * 8 + t) * 128 + d], acc);
  ws[G_OFF + ((t * 128 + e) << 7) + d] = acc;
}

// ---------------------------------------------------------------------------
// main: conv -> split-f16 MFMA distances -> argmin (+rare fp64 rescan) ->
// out via G-table gather-sum. Hot path is wave-local (no mid-kernel barrier).
// ---------------------------------------------------------------------------
__global__ __launch_bounds__(256, 3) void main_kernel(
    const float* __restrict__ fn, const unsigned char* __restrict__ mask,
    const float* __restrict__ conv_w, const float* __restrict__ conv_b,
    const float* __restrict__ codebook, float* __restrict__ ws,
    float* __restrict__ out)
{
  __shared__ __align__(16) float ncl[NE * 12];       // positive codebook rows
  __shared__ __align__(16) _Float16 zA[256 * 40];    // A-frags: zh|1|zl|1 packed
  __shared__ int idxp[256];
  __shared__ unsigned hist[NE];
  __shared__ float sqacc;

  const int tid = threadIdx.x;

  // ---- cooperative fills ----
  if (tid < NE) {
#pragma unroll
    for (int c = 0; c < NC; ++c) ncl[tid * 12 + c] = codebook[tid * NC + c];
    hist[tid] = 0u;
  }
  if (tid == 255) sqacc = 0.f;

  // B-frag preload (global, no barrier needed)
  const int lane = tid & 63, w = tid >> 6;
  const int rl = lane & 15, q = lane >> 4;
  const half8* bhp = (const half8*)((const char*)ws + BH_OFF * 4);
  const half8* blp = (const half8*)((const char*)ws + BL_OFF * 4);
  half8 Bh[8], Bl[8];
#pragma unroll
  for (int nt = 0; nt < 8; ++nt) { Bh[nt] = bhp[nt * 64 + lane]; Bl[nt] = blp[nt * 64 + lane]; }
  int ent[8];
#pragma unroll
  for (int nt = 0; nt < 8; ++nt) ent[nt] = nt * 16 + rl;

  __syncthreads();   // for ncl + hist + sqacc

  // ---- stage 1: conv, one (b,t) position per thread p = tid ----
  const int p = tid;
  const int bg = blockIdx.x * BB + (p >> 3);         // global batch row
  const float4 pv = ((const float4*)fn)[blockIdx.x * 256 + p];
  float z[NC];
#pragma unroll
  for (int c = 0; c < NC; ++c) {
    float pre = fmaf(pv.w, conv_w[c * 4 + 3], fmaf(pv.z, conv_w[c * 4 + 2],
                fmaf(pv.y, conv_w[c * 4 + 1], fmaf(pv.x, conv_w[c * 4 + 0], conv_b[c]))));
    z[c] = pre > 0.f ? pre : 0.f;
  }
  // split to f16 hi/lo, pack A-frag row: k0..9=zh, k10=1, k16..25=zl, k26=1
  half8 v0, v1, v2, v3;
#pragma unroll
  for (int c = 0; c < 8; ++c) {
    _Float16 zh = (_Float16)z[c];
    v0[c] = zh; v2[c] = (_Float16)(z[c] - (float)zh);
  }
  {
    _Float16 z8 = (_Float16)z[8], z9 = (_Float16)z[9];
    v1 = (half8){z8, z9, (_Float16)1.f, 0, 0, 0, 0, 0};
    v3 = (half8){(_Float16)(z[8] - (float)z8), (_Float16)(z[9] - (float)z9),
                 (_Float16)1.f, 0, 0, 0, 0, 0};
  }
  {
    half8* zrow = (half8*)&zA[p * 40];
    zrow[0] = v0; zrow[1] = v1; zrow[2] = v2; zrow[3] = v3;
  }

  // ---- stage 2: VQ distances via MFMA + argmin (wave-local) ----
  for (int m = 0; m < 4; ++m) {
    const int mt = w * 4 + m;
    const half8 a = *(const half8*)&zA[(mt * 16 + rl) * 40 + q * 8];
    f32x4 acc[8];
#pragma unroll
    for (int nt = 0; nt < 8; ++nt) {
      f32x4 zero = {0.f, 0.f, 0.f, 0.f};
      acc[nt] = __builtin_amdgcn_mfma_f32_16x16x32_f16(a, Bh[nt], zero, 0, 0, 0);
      acc[nt] = __builtin_amdgcn_mfma_f32_16x16x32_f16(a, Bl[nt], acc[nt], 0, 0, 0);
    }
#pragma unroll
    for (int r = 0; r < 4; ++r) {
      // min value over 8 regs then 16 lanes
      float mv = fminf(fminf(fminf(acc[0][r], acc[1][r]), fminf(acc[2][r], acc[3][r])),
                       fminf(fminf(acc[4][r], acc[5][r]), fminf(acc[6][r], acc[7][r])));
#pragma unroll
      for (int s = 1; s < 16; s <<= 1) mv = fminf(mv, __shfl_xor(mv, s, 16));
      // smallest index attaining mv
      int ii = 1 << 20;
#pragma unroll
      for (int nt = 7; nt >= 0; --nt) ii = (acc[nt][r] == mv) ? ent[nt] : ii;
#pragma unroll
      for (int s = 1; s < 16; s <<= 1) { int o = __shfl_xor(ii, s, 16); ii = o < ii ? o : ii; }
      // near-tie flag: count entries within threshold of mv
      const float mvt = mv + 1.5e-4f;
      int cnt = 0;
#pragma unroll
      for (int nt = 0; nt < 8; ++nt) cnt += (acc[nt][r] < mvt) ? 1 : 0;
#pragma unroll
      for (int s = 1; s < 16; s <<= 1) cnt += __shfl_xor(cnt, s, 16);
      if (rl == r) idxp[mt * 16 + q * 4 + r] = ii | (cnt >= 2 ? (int)0x80000000 : 0);
    }
  }

  // ---- owner finalize: rare fp64 rescan, sq-err, histogram ----
  int pk = idxp[p];
  int bi = pk & 127;
  if (pk < 0) {
    double bd = 1e300; int bb = 0;
    for (int e = 0; e < NE; ++e) {
      double s = 0.0;
#pragma unroll
      for (int c = 0; c < NC; ++c) {
        double df = (double)z[c] - (double)ncl[e * 12 + c];
        s = fma(df, df, s);
      }
      if (s < bd) { bd = s; bb = e; }
    }
    bi = bb;
    idxp[p] = bi;
  }
  float sq = 0.f;
  {
    const float4 q0 = *(const float4*)&ncl[bi * 12];
    const float4 q1 = *(const float4*)&ncl[bi * 12 + 4];
    const float2 q2 = *(const float2*)&ncl[bi * 12 + 8];
    const float qq[10] = {q0.x, q0.y, q0.z, q0.w, q1.x, q1.y, q1.z, q1.w, q2.x, q2.y};
#pragma unroll
    for (int c = 0; c < NC; ++c) { float df = qq[c] - z[c]; sq = fmaf(df, df, sq); }
  }
  const bool valid = (mask[bg] == 0);
  float sv = valid ? sq : 0.f;
#pragma unroll
  for (int off = 32; off > 0; off >>= 1) sv += __shfl_down(sv, off);
  if (lane == 0) atomicAdd(&sqacc, sv);
  if (valid) atomicAdd(&hist[bi], 1u);

  // ---- stage 3: out[b][:] = b2 + sum_t G[t][idx[b,t]][:]  (wave-local idx) ----
  const int b_loc = tid >> 3, dc = tid & 7;
  int idx8[8];
  {
    const int4 i0 = *(const int4*)&idxp[b_loc * 8];
    const int4 i1 = *(const int4*)&idxp[b_loc * 8 + 4];
    idx8[0] = i0.x; idx8[1] = i0.y; idx8[2] = i0.z; idx8[3] = i0.w;
    idx8[4] = i1.x; idx8[5] = i1.y; idx8[6] = i1.z; idx8[7] = i1.w;
  }
  float4 a0 = {0, 0, 0, 0}, a1 = {0, 0, 0, 0}, a2 = {0, 0, 0, 0}, a3 = {0, 0, 0, 0};
#pragma unroll
  for (int t = 0; t < 8; ++t) {
    const int e = idx8[t] & 127;
    const float4* gp = (const float4*)&ws[G_OFF + ((t * 128 + e) << 7)];
    const float4 g0 = gp[0 * 8 + dc], g1 = gp[1 * 8 + dc];
    const float4 g2 = gp[2 * 8 + dc], g3 = gp[3 * 8 + dc];
    a0.x += g0.x; a0.y += g0.y; a0.z += g0.z; a0.w += g0.w;
    a1.x += g1.x; a1.y += g1.y; a1.z += g1.z; a1.w += g1.w;
    a2.x += g2.x; a2.y += g2.y; a2.z += g2.z; a2.w += g2.w;
    a3.x += g3.x; a3.y += g3.y; a3.z += g3.z; a3.w += g3.w;
  }
  {
    const float4* bp = (const float4*)&ws[B2_OFF];
    const float4 b0 = bp[0 * 8 + dc], b1 = bp[1 * 8 + dc];
    const float4 b2v = bp[2 * 8 + dc], b3 = bp[3 * 8 + dc];
    a0.x += b0.x; a0.y += b0.y; a0.z += b0.z; a0.w += b0.w;
    a1.x += b1.x; a1.y += b1.y; a1.z += b1.z; a1.w += b1.w;
    a2.x += b2v.x; a2.y += b2v.y; a2.z += b2v.z; a2.w += b2v.w;
    a3.x += b3.x; a3.y += b3.y; a3.z += b3.z; a3.w += b3.w;
    float4* op = (float4*)&out[(size_t)(blockIdx.x * BB + b_loc) * ZD];
    op[0 * 8 + dc] = a0; op[1 * 8 + dc] = a1; op[2 * 8 + dc] = a2; op[3 * 8 + dc] = a3;
  }

  // ---- global accumulation ----
  __syncthreads();
  if (tid == 0) atomicAdd(&ws[SQ_OFF], sqacc);
  if (tid < NE) { unsigned h = hist[tid]; if (h) atomicAdd(&((unsigned*)ws)[CT_OFF + tid], h); }
}

// ---------------------------------------------------------------------------
// fin: cmt_loss and perplexity.
// ---------------------------------------------------------------------------
__global__ __launch_bounds__(128) void fin_kernel(const float* __restrict__ ws,
                                                  float* __restrict__ out)
{
  __shared__ float red[NE];
  const int tid = threadIdx.x;
  const unsigned c = ((const unsigned*)ws)[CT_OFF + tid];
  const float cf = (float)c;
  red[tid] = cf;
  __syncthreads();
  for (int s = 64; s > 0; s >>= 1) { if (tid < s) red[tid] += red[tid + s]; __syncthreads(); }
  const float vfsum = red[0];
  __syncthreads();
  const float pr = cf / vfsum;
  red[tid] = pr * logf(pr + 1e-10f);
  __syncthreads();
  for (int s = 64; s > 0; s >>= 1) { if (tid < s) red[tid] += red[tid + s]; __syncthreads(); }
  if (tid == 0) {
    const float ent = red[0];
    const float e_latent = ws[SQ_OFF] / (vfsum * (float)NC);
    out[(size_t)BSZ * ZD + 0] = CCF * e_latent;
    out[(size_t)BSZ * ZD + 1] = expf(-ent);
  }
}

// ---------------------------------------------------------------------------
extern "C" void kernel_launch(void* const* d_in, const int* in_sizes, int n_in,
                              void* d_out, int out_size, void* d_ws, size_t ws_size,
                              hipStream_t stream)
{
  const float* fn           = (const float*)d_in[0];
  const unsigned char* mask = (const unsigned char*)d_in[1];
  const float* conv_w       = (const float*)d_in[2];
  const float* conv_b       = (const float*)d_in[3];
  const float* codebook     = (const float*)d_in[4];
  const float* fc_w         = (const float*)d_in[5];
  const float* fc_b         = (const float*)d_in[6];
  const float* mu_w         = (const float*)d_in[7];
  const float* mu_b         = (const float*)d_in[8];
  float* out = (float*)d_out;
  float* ws  = (float*)d_ws;

  hipLaunchKernelGGL(prep1_kernel, dim3(83), dim3(256), 0, stream,
                     codebook, fc_w, fc_b, mu_w, mu_b, ws);
  hipLaunchKernelGGL(prep2_kernel, dim3(1024), dim3(128), 0, stream, codebook, ws);
  hipLaunchKernelGGL(main_kernel, dim3(BSZ / BB), dim3(256), 0, stream,
                     fn, mask, conv_w, conv_b, codebook, ws, out);
  hipLaunchKernelGGL(fin_kernel, dim3(1), dim3(128), 0, stream, ws, out);
}

// Round 4
// 148.213 us; speedup vs baseline: 1.0894x; 1.0894x over previous
//
#include <hip/hip_runtime.h>
#include <math.h>

#define BSZ 65536
#define NC 10
#define T 8
#define NE 128
#define EMB 256
#define ZD 128
#define NCT 80
#define CCF 0.25f
#define BB 32

// ws float offsets
#define WT_OFF  0        // Wt[80][128] fp32, k-major (W[d][k] = Wt[k*128+d])
#define B2_OFF  10240    // 128 fused bias
#define NC_OFF  10368    // neg codebook [128][12]: 0-9=-c, 10=cn/2, 11=pad
#define CT_OFF  11904    // 128 u32 histogram
#define SQ_OFF  12032    // 1 float sq-err accumulator
#define G_OFF   16384    // G[8][128][128] fp32 gather table (512 KB)

// ---------------------------------------------------------------------------
// prep1: Wt = (mu_w@fc_w)^T fp32; b2 = mu_w@fc_b + mu_b; negated codebook
// table (+cn/2); zero accumulators.
// ---------------------------------------------------------------------------
__global__ __launch_bounds__(256) void prep1_kernel(
    const float* __restrict__ codebook, const float* __restrict__ fc_w,
    const float* __restrict__ fc_b, const float* __restrict__ mu_w,
    const float* __restrict__ mu_b, float* __restrict__ ws)
{
  const int blk = blockIdx.x, tid = threadIdx.x;
  if (blk < 80) {                       // 80*256/2 = 10240 W elements
    const int gi = blk * 256 + tid;
    const int idx = gi >> 1, h = gi & 1;
    const int d = idx / NCT, k = idx - d * NCT;
    const float* mw = mu_w + d * EMB + h * 128;
    const float* fw = fc_w + (h * 128) * NCT + k;
    float acc = 0.f;
#pragma unroll 8
    for (int e = 0; e < 128; ++e) acc = fmaf(mw[e], fw[e * NCT], acc);
    acc += __shfl_xor(acc, 1);
    if (h == 0) ws[WT_OFF + k * 128 + d] = acc;
  } else if (blk == 80) {               // b2
    const int d = tid >> 1, h = tid & 1;
    const float* mw = mu_w + d * EMB + h * 128;
    const float* fb = fc_b + h * 128;
    float acc = 0.f;
#pragma unroll 8
    for (int e = 0; e < 128; ++e) acc = fmaf(mw[e], fb[e], acc);
    acc += __shfl_xor(acc, 1);
    if (h == 0) ws[B2_OFF + d] = acc + mu_b[d];
  } else {                              // blk 81: neg-codebook table + zeros
    if (tid < NE) {
      float cn = 0.f;
      for (int c = 0; c < NC; ++c) {
        float v = codebook[tid * NC + c];
        ws[NC_OFF + tid * 12 + c] = -v;
        cn = fmaf(v, v, cn);
      }
      ws[NC_OFF + tid * 12 + 10] = 0.5f * cn;
      ws[NC_OFF + tid * 12 + 11] = 0.f;
      ((unsigned*)ws)[CT_OFF + tid] = 0u;
    }
    if (tid == 0) ws[SQ_OFF] = 0.f;
  }
}

// ---------------------------------------------------------------------------
// prep2: G[t][e][d] = sum_c cb[e][c] * W[d][c*8+t]   (needs Wt complete)
// ---------------------------------------------------------------------------
__global__ __launch_bounds__(128) void prep2_kernel(
    const float* __restrict__ codebook, float* __restrict__ ws)
{
  const int t = blockIdx.x >> 7, e = blockIdx.x & 127, d = threadIdx.x;
  float acc = 0.f;
#pragma unroll
  for (int c = 0; c < NC; ++c)
    acc = fmaf(codebook[e * NC + c], ws[WT_OFF + (c * 8 + t) * 128 + d], acc);
  ws[G_OFF + ((t * 128 + e) << 7) + d] = acc;
}

// ---------------------------------------------------------------------------
// main: conv -> pure-VALU dual-tracker VQ scan (broadcast LDS reads, no
// cross-lane ops) -> out via G-table gather. No MFMA, no mid-kernel barrier.
// ---------------------------------------------------------------------------
__global__ __launch_bounds__(256, 4) void main_kernel(
    const float* __restrict__ fn, const unsigned char* __restrict__ mask,
    const float* __restrict__ conv_w, const float* __restrict__ conv_b,
    float* __restrict__ ws, float* __restrict__ out)
{
  __shared__ __align__(16) float ncl[NE * 12];   // 6144 B
  __shared__ int idxp[256];
  __shared__ unsigned hist[NE];
  __shared__ float sqacc;

  const int tid = threadIdx.x;
  const int lane = tid & 63;

  // ---- cooperative fills ----
  {
    const float4* src = (const float4*)(ws + NC_OFF);
    float4* dst = (float4*)ncl;
    dst[tid] = src[tid];
    if (tid < NE * 3 - 256) dst[tid + 256] = src[tid + 256];
  }
  if (tid < NE) hist[tid] = 0u;
  if (tid == 255) sqacc = 0.f;
  __syncthreads();

  // ---- stage 1: conv, one (b,t) per thread ----
  const int bg = blockIdx.x * BB + (tid >> 3);
  const float4 pv = ((const float4*)fn)[blockIdx.x * 256 + tid];
  float z[NC];
#pragma unroll
  for (int c = 0; c < NC; ++c) {
    float pre = fmaf(pv.w, conv_w[c * 4 + 3], fmaf(pv.z, conv_w[c * 4 + 2],
                fmaf(pv.y, conv_w[c * 4 + 1], fmaf(pv.x, conv_w[c * 4 + 0], conv_b[c]))));
    z[c] = pre > 0.f ? pre : 0.f;
  }
  float zn = 0.f;
#pragma unroll
  for (int c = 0; c < NC; ++c) zn = fmaf(z[c], z[c], zn);

  // ---- stage 2: VQ scan, d' = cn/2 - z.c, dual independent trackers ----
  float bA = 3.4e38f, b2A = 3.4e38f, bB = 3.4e38f, b2B = 3.4e38f;
  int iA = 0, i2A = 0, iB = 1, i2B = 1;
  const float4* nc4 = (const float4*)ncl;
#pragma unroll 2
  for (int e = 0; e < NE; e += 2) {
    const float4 a0 = nc4[e * 3 + 0], a1 = nc4[e * 3 + 1], a2 = nc4[e * 3 + 2];
    const float4 c0 = nc4[e * 3 + 3], c1 = nc4[e * 3 + 4], c2 = nc4[e * 3 + 5];
    float dA = fmaf(z[0], a0.x, a2.z);
    float dB = fmaf(z[0], c0.x, c2.z);
    dA = fmaf(z[1], a0.y, dA); dB = fmaf(z[1], c0.y, dB);
    dA = fmaf(z[2], a0.z, dA); dB = fmaf(z[2], c0.z, dB);
    dA = fmaf(z[3], a0.w, dA); dB = fmaf(z[3], c0.w, dB);
    dA = fmaf(z[4], a1.x, dA); dB = fmaf(z[4], c1.x, dB);
    dA = fmaf(z[5], a1.y, dA); dB = fmaf(z[5], c1.y, dB);
    dA = fmaf(z[6], a1.z, dA); dB = fmaf(z[6], c1.z, dB);
    dA = fmaf(z[7], a1.w, dA); dB = fmaf(z[7], c1.w, dB);
    dA = fmaf(z[8], a2.x, dA); dB = fmaf(z[8], c2.x, dB);
    dA = fmaf(z[9], a2.y, dA); dB = fmaf(z[9], c2.y, dB);
    if (dA < bA)       { b2A = bA; i2A = iA; bA = dA; iA = e; }
    else if (dA < b2A) { b2A = dA; i2A = e; }
    if (dB < bB)       { b2B = bB; i2B = iB; bB = dB; iB = e + 1; }
    else if (dB < b2B) { b2B = dB; i2B = e + 1; }
  }
  // merge trackers -> global top-2
  float best, best2; int bi, bi2;
  if (bA <= bB) {
    best = bA; bi = iA;
    if (bB <= b2A) { best2 = bB; bi2 = iB; } else { best2 = b2A; bi2 = i2A; }
  } else {
    best = bB; bi = iB;
    if (bA <= b2B) { best2 = bA; bi2 = iA; } else { best2 = b2B; bi2 = i2B; }
  }
  // near-tie: fp64 pair recheck (rare divergent path), matches reference argmin
  if ((best2 - best) * 2.f < 1e-3f * (fabsf(2.f * best + zn) + 1.f)) {
    double s1 = 0.0, s2 = 0.0;
    for (int c = 0; c < NC; ++c) {
      double a = (double)z[c] + (double)ncl[bi * 12 + c];
      double q2 = (double)z[c] + (double)ncl[bi2 * 12 + c];
      s1 += a * a; s2 += q2 * q2;
    }
    if (s2 < s1 || (s2 == s1 && bi2 < bi)) bi = bi2;
  }
  idxp[tid] = bi;

  // ---- sq-err + histogram ----
  float sq = 0.f;
#pragma unroll
  for (int c = 0; c < NC; ++c) {
    float df = z[c] + ncl[bi * 12 + c];     // z - cb
    sq = fmaf(df, df, sq);
  }
  const bool valid = (mask[bg] == 0);
  float sv = valid ? sq : 0.f;
#pragma unroll
  for (int off = 32; off > 0; off >>= 1) sv += __shfl_down(sv, off);
  if (lane == 0) atomicAdd(&sqacc, sv);
  if (valid) atomicAdd(&hist[bi], 1u);

  // ---- stage 3: out[b][:] = b2 + sum_t G[t][idx[b,t]][:] (wave-local idx) ----
  const int b_loc = tid >> 3, dc = tid & 7;
  int idx8[8];
  {
    const int4 i0 = *(const int4*)&idxp[b_loc * 8];
    const int4 i1 = *(const int4*)&idxp[b_loc * 8 + 4];
    idx8[0] = i0.x; idx8[1] = i0.y; idx8[2] = i0.z; idx8[3] = i0.w;
    idx8[4] = i1.x; idx8[5] = i1.y; idx8[6] = i1.z; idx8[7] = i1.w;
  }
  float4 a0 = {0, 0, 0, 0}, a1 = {0, 0, 0, 0}, a2 = {0, 0, 0, 0}, a3 = {0, 0, 0, 0};
#pragma unroll
  for (int t = 0; t < 8; ++t) {
    const float4* gp = (const float4*)&ws[G_OFF + ((t * 128 + idx8[t]) << 7)];
    const float4 g0 = gp[0 * 8 + dc], g1 = gp[1 * 8 + dc];
    const float4 g2 = gp[2 * 8 + dc], g3 = gp[3 * 8 + dc];
    a0.x += g0.x; a0.y += g0.y; a0.z += g0.z; a0.w += g0.w;
    a1.x += g1.x; a1.y += g1.y; a1.z += g1.z; a1.w += g1.w;
    a2.x += g2.x; a2.y += g2.y; a2.z += g2.z; a2.w += g2.w;
    a3.x += g3.x; a3.y += g3.y; a3.z += g3.z; a3.w += g3.w;
  }
  {
    const float4* bp = (const float4*)&ws[B2_OFF];
    const float4 b0 = bp[0 * 8 + dc], b1 = bp[1 * 8 + dc];
    const float4 b2v = bp[2 * 8 + dc], b3 = bp[3 * 8 + dc];
    a0.x += b0.x; a0.y += b0.y; a0.z += b0.z; a0.w += b0.w;
    a1.x += b1.x; a1.y += b1.y; a1.z += b1.z; a1.w += b1.w;
    a2.x += b2v.x; a2.y += b2v.y; a2.z += b2v.z; a2.w += b2v.w;
    a3.x += b3.x; a3.y += b3.y; a3.z += b3.z; a3.w += b3.w;
    float4* op = (float4*)&out[(size_t)(blockIdx.x * BB + b_loc) * ZD];
    op[0 * 8 + dc] = a0; op[1 * 8 + dc] = a1; op[2 * 8 + dc] = a2; op[3 * 8 + dc] = a3;
  }

  // ---- global accumulation ----
  __syncthreads();
  if (tid == 0) atomicAdd(&ws[SQ_OFF], sqacc);
  if (tid < NE) { unsigned h = hist[tid]; if (h) atomicAdd(&((unsigned*)ws)[CT_OFF + tid], h); }
}

// ---------------------------------------------------------------------------
// fin: cmt_loss and perplexity.
// ---------------------------------------------------------------------------
__global__ __launch_bounds__(128) void fin_kernel(const float* __restrict__ ws,
                                                  float* __restrict__ out)
{
  __shared__ float red[NE];
  const int tid = threadIdx.x;
  const unsigned c = ((const unsigned*)ws)[CT_OFF + tid];
  const float cf = (float)c;
  red[tid] = cf;
  __syncthreads();
  for (int s = 64; s > 0; s >>= 1) { if (tid < s) red[tid] += red[tid + s]; __syncthreads(); }
  const float vfsum = red[0];
  __syncthreads();
  const float pr = cf / vfsum;
  red[tid] = pr * logf(pr + 1e-10f);
  __syncthreads();
  for (int s = 64; s > 0; s >>= 1) { if (tid < s) red[tid] += red[tid + s]; __syncthreads(); }
  if (tid == 0) {
    const float ent = red[0];
    const float e_latent = ws[SQ_OFF] / (vfsum * (float)NC);
    out[(size_t)BSZ * ZD + 0] = CCF * e_latent;
    out[(size_t)BSZ * ZD + 1] = expf(-ent);
  }
}

// ---------------------------------------------------------------------------
extern "C" void kernel_launch(void* const* d_in, const int* in_sizes, int n_in,
                              void* d_out, int out_size, void* d_ws, size_t ws_size,
                              hipStream_t stream)
{
  const float* fn           = (const float*)d_in[0];
  const unsigned char* mask = (const unsigned char*)d_in[1];
  const float* conv_w       = (const float*)d_in[2];
  const float* conv_b       = (const float*)d_in[3];
  const float* codebook     = (const float*)d_in[4];
  const float* fc_w         = (const float*)d_in[5];
  const float* fc_b         = (const float*)d_in[6];
  const float* mu_w         = (const float*)d_in[7];
  const float* mu_b         = (const float*)d_in[8];
  float* out = (float*)d_out;
  float* ws  = (float*)d_ws;

  hipLaunchKernelGGL(prep1_kernel, dim3(82), dim3(256), 0, stream,
                     codebook, fc_w, fc_b, mu_w, mu_b, ws);
  hipLaunchKernelGGL(prep2_kernel, dim3(1024), dim3(128), 0, stream, codebook, ws);
  hipLaunchKernelGGL(main_kernel, dim3(BSZ / BB), dim3(256), 0, stream,
                     fn, mask, conv_w, conv_b, ws, out);
  hipLaunchKernelGGL(fin_kernel, dim3(1), dim3(128), 0, stream, ws, out);
}

// Round 5
// 139.780 us; speedup vs baseline: 1.1552x; 1.0603x over previous
//
#include <hip/hip_runtime.h>
#include <math.h>

#define BSZ 65536
#define NC 10
#define T 8
#define NE 128
#define EMB 256
#define ZD 128
#define NCT 80
#define CCF 0.25f
#define BB 32

// ws float offsets
#define WT_OFF  0        // Wt[80][128] fp32, k-major
#define B2_OFF  10240    // 128 fused bias
#define NC_OFF  10368    // neg codebook [128][12]: 0-9=-c, 10=cn/2, 11=pad
#define CT_OFF  11904    // 128 u32 histogram
#define SQ_OFF  12032    // 1 float sq-err accumulator
#define AH_OFF  12288    // 2048 floats = 4096 halves: MFMA A-frag table [8][64] half8
#define G_OFF   16384    // G[8][128][128] fp32 gather table (512 KB)

typedef _Float16 half8 __attribute__((ext_vector_type(8)));
typedef float f32x4 __attribute__((ext_vector_type(4)));

// ---------------------------------------------------------------------------
// prep1: Wt, b2, neg-codebook table, zeros, and the MFMA A-fragment table.
// A-slot layout (K=32): 0-9=-ch, 10-19=-cl, 20-29=-ch, 30=cn/2 hi, 31=cn/2 lo.
// Entry id bit-layout within a 16-tile: entry = nt*16 + reg*4 + quad, so the
// A row m=quad*4+reg holds codebook entry nt*16 + (m&3)*4 + (m>>2).
// ---------------------------------------------------------------------------
__global__ __launch_bounds__(256) void prep1_kernel(
    const float* __restrict__ codebook, const float* __restrict__ fc_w,
    const float* __restrict__ fc_b, const float* __restrict__ mu_w,
    const float* __restrict__ mu_b, float* __restrict__ ws)
{
  const int blk = blockIdx.x, tid = threadIdx.x;
  if (blk < 80) {                       // W = mu_w@fc_w, transposed store
    const int gi = blk * 256 + tid;
    const int idx = gi >> 1, h = gi & 1;
    const int d = idx / NCT, k = idx - d * NCT;
    const float* mw = mu_w + d * EMB + h * 128;
    const float* fw = fc_w + (h * 128) * NCT + k;
    float acc = 0.f;
#pragma unroll 8
    for (int e = 0; e < 128; ++e) acc = fmaf(mw[e], fw[e * NCT], acc);
    acc += __shfl_xor(acc, 1);
    if (h == 0) ws[WT_OFF + k * 128 + d] = acc;
  } else if (blk == 80) {               // b2
    const int d = tid >> 1, h = tid & 1;
    const float* mw = mu_w + d * EMB + h * 128;
    const float* fb = fc_b + h * 128;
    float acc = 0.f;
#pragma unroll 8
    for (int e = 0; e < 128; ++e) acc = fmaf(mw[e], fb[e], acc);
    acc += __shfl_xor(acc, 1);
    if (h == 0) ws[B2_OFF + d] = acc + mu_b[d];
  } else if (blk == 81) {               // neg-codebook table + zeros
    if (tid < NE) {
      float cn = 0.f;
      for (int c = 0; c < NC; ++c) {
        float v = codebook[tid * NC + c];
        ws[NC_OFF + tid * 12 + c] = -v;
        cn = fmaf(v, v, cn);
      }
      ws[NC_OFF + tid * 12 + 10] = 0.5f * cn;
      ws[NC_OFF + tid * 12 + 11] = 0.f;
      ((unsigned*)ws)[CT_OFF + tid] = 0u;
    }
    if (tid == 0) ws[SQ_OFF] = 0.f;
  } else {                              // blk 82/83: A-frag tables
    const int nt = (blk - 82) * 4 + (tid >> 6);
    const int lane = tid & 63;
    const int rl = lane & 15, q = lane >> 4;
    const int X = nt * 16 + ((rl & 3) << 2) + (rl >> 2);
    float cb_[NC]; float cn = 0.f;
#pragma unroll
    for (int c = 0; c < NC; ++c) { cb_[c] = codebook[X * NC + c]; cn = fmaf(cb_[c], cb_[c], cn); }
    const float cn2 = 0.5f * cn;
    const _Float16 cnh = (_Float16)cn2;
    const _Float16 cnl = (_Float16)(cn2 - (float)cnh);
    half8 hv;
#pragma unroll
    for (int j = 0; j < 8; ++j) {
      const int s = q * 8 + j;
      _Float16 val;
      if (s < 10) {
        val = (_Float16)(-cb_[s]);
      } else if (s < 20) {
        float m = -cb_[s - 10];
        _Float16 mh = (_Float16)m;
        val = (_Float16)(m - (float)mh);
      } else if (s < 30) {
        val = (_Float16)(-cb_[s - 20]);
      } else if (s == 30) val = cnh; else val = cnl;
      hv[j] = val;
    }
    ((half8*)(ws + AH_OFF))[nt * 64 + lane] = hv;
  }
}

// ---------------------------------------------------------------------------
// prep2: G[t][e][d] = sum_c cb[e][c] * W[d][c*8+t]
// ---------------------------------------------------------------------------
__global__ __launch_bounds__(128) void prep2_kernel(
    const float* __restrict__ codebook, float* __restrict__ ws)
{
  const int t = blockIdx.x >> 7, e = blockIdx.x & 127, d = threadIdx.x;
  float acc = 0.f;
#pragma unroll
  for (int c = 0; c < NC; ++c)
    acc = fmaf(codebook[e * NC + c], ws[WT_OFF + (c * 8 + t) * 128 + d], acc);
  ws[G_OFF + ((t * 128 + e) << 7) + d] = acc;
}

// ---------------------------------------------------------------------------
// main: conv -> transposed-MFMA distances (entries in D-rows, positions in
// D-cols -> lane-local argmin) -> u32-key exact top-2 -> fp64 pair recheck ->
// G-table gather.
// ---------------------------------------------------------------------------
__global__ __launch_bounds__(256, 4) void main_kernel(
    const float* __restrict__ fn, const unsigned char* __restrict__ mask,
    const float* __restrict__ conv_w, const float* __restrict__ conv_b,
    float* __restrict__ ws, float* __restrict__ out)
{
  __shared__ __align__(16) float ncl[NE * 12];        // 6144 B
  __shared__ __align__(16) _Float16 zB[256 * 32];     // 16384 B packed B-vectors
  __shared__ float znA[256];
  __shared__ uint2 kres[256];
  __shared__ int idxp[256];
  __shared__ unsigned hist[NE];
  __shared__ float sqacc;

  const int tid = threadIdx.x;
  const int lane = tid & 63, w = tid >> 6;
  const int rl = lane & 15, qd = lane >> 4;

  // ---- A-frag preload (global, latency hidden under conv) ----
  const half8* ahp = (const half8*)(ws + AH_OFF);
  half8 A[8];
#pragma unroll
  for (int nt = 0; nt < 8; ++nt) A[nt] = ahp[nt * 64 + lane];

  // ---- conv, one (b,t) per thread ----
  const float4 pv = ((const float4*)fn)[blockIdx.x * 256 + tid];
  float z[NC];
#pragma unroll
  for (int c = 0; c < NC; ++c) {
    float pre = fmaf(pv.w, conv_w[c * 4 + 3], fmaf(pv.z, conv_w[c * 4 + 2],
                fmaf(pv.y, conv_w[c * 4 + 1], fmaf(pv.x, conv_w[c * 4 + 0], conv_b[c]))));
    z[c] = pre > 0.f ? pre : 0.f;
  }
  float zn = 0.f;
#pragma unroll
  for (int c = 0; c < NC; ++c) zn = fmaf(z[c], z[c], zn);
  znA[tid] = 0.5f * zn;

  // split z to f16 hi/lo and pack B-vector: slots 0-9=zh, 10-19=zh, 20-29=zl, 30,31=1
  _Float16 zh[NC], zl[NC];
#pragma unroll
  for (int c = 0; c < NC; ++c) {
    zh[c] = (_Float16)z[c];
    zl[c] = (_Float16)(z[c] - (float)zh[c]);
  }
  {
    half8* zrow = (half8*)&zB[tid * 32];
    zrow[0] = (half8){zh[0], zh[1], zh[2], zh[3], zh[4], zh[5], zh[6], zh[7]};
    zrow[1] = (half8){zh[8], zh[9], zh[0], zh[1], zh[2], zh[3], zh[4], zh[5]};
    zrow[2] = (half8){zh[6], zh[7], zh[8], zh[9], zl[0], zl[1], zl[2], zl[3]};
    zrow[3] = (half8){zl[4], zl[5], zl[6], zl[7], zl[8], zl[9],
                      (_Float16)1.f, (_Float16)1.f};
  }

  // ---- cooperative fills ----
  {
    const float4* src = (const float4*)(ws + NC_OFF);
    float4* dst = (float4*)ncl;
    dst[tid] = src[tid];
    if (tid < NE * 3 - 256) dst[tid + 256] = src[tid + 256];
  }
  if (tid < NE) hist[tid] = 0u;
  if (tid == 255) sqacc = 0.f;
  __syncthreads();

  // ---- MFMA distance + lane-local top-2 keys, per 16-position group ----
  for (int mt = 0; mt < 4; ++mt) {
    const int wpos = w * 64 + mt * 16 + rl;
    const half8 bf = *(const half8*)&zB[wpos * 32 + qd * 8];
    const float zn2 = znA[wpos];
    const f32x4 cinit = {zn2, zn2, zn2, zn2};
    unsigned b1 = 0xFFFFFFFFu, b2 = 0xFFFFFFFFu;
#pragma unroll
    for (int nt = 0; nt < 8; ++nt) {
      const f32x4 acc = __builtin_amdgcn_mfma_f32_16x16x32_f16(A[nt], bf, cinit, 0, 0, 0);
#pragma unroll
      for (int reg = 0; reg < 4; ++reg) {
        const unsigned u = __float_as_uint(acc[reg]);
        const unsigned key = ((u & 0xFFFFFF80u) | (unsigned)qd) + (unsigned)(nt * 16 + reg * 4);
        const unsigned t = b1 > key ? b1 : key;
        b1 = b1 < key ? b1 : key;
        b2 = b2 < t ? b2 : t;
      }
    }
    // cross-quad top-2 merge (positions live in cols; quads hold disjoint rows)
#pragma unroll
    for (int s = 16; s <= 32; s <<= 1) {
      const unsigned o1 = (unsigned)__shfl_xor((int)b1, s);
      const unsigned o2 = (unsigned)__shfl_xor((int)b2, s);
      const unsigned t = b1 > o1 ? b1 : o1;
      b1 = b1 < o1 ? b1 : o1;
      b2 = b2 < o2 ? b2 : o2;
      b2 = b2 < t ? b2 : t;
    }
    if (lane < 16) kres[wpos] = make_uint2(b1, b2);
  }

  // ---- owner finalize: tie recheck, sq-err, histogram ----
  const uint2 kk = kres[tid];
  int bi = (int)(kk.x & 127u);
  {
    const int bi2 = (int)(kk.y & 127u);
    const float v1 = __uint_as_float(kk.x & 0xFFFFFF80u);
    const float v2 = __uint_as_float(kk.y & 0xFFFFFF80u);
    if (v2 - v1 < fmaf(1e-4f, v1, 1e-4f)) {
      double s1 = 0.0, s2 = 0.0;
      for (int c = 0; c < NC; ++c) {
        double a = (double)z[c] + (double)ncl[bi * 12 + c];
        double q2 = (double)z[c] + (double)ncl[bi2 * 12 + c];
        s1 += a * a; s2 += q2 * q2;
      }
      if (s2 < s1 || (s2 == s1 && bi2 < bi)) bi = bi2;
    }
  }
  idxp[tid] = bi;

  float sq = 0.f;
#pragma unroll
  for (int c = 0; c < NC; ++c) {
    float df = z[c] + ncl[bi * 12 + c];     // z - cb
    sq = fmaf(df, df, sq);
  }
  const int bg = blockIdx.x * BB + (tid >> 3);
  const bool valid = (mask[bg] == 0);
  float sv = valid ? sq : 0.f;
#pragma unroll
  for (int off = 32; off > 0; off >>= 1) sv += __shfl_down(sv, off);
  if (lane == 0) atomicAdd(&sqacc, sv);
  if (valid) atomicAdd(&hist[bi], 1u);

  // ---- stage 3: out[b][:] = b2 + sum_t G[t][idx[b,t]][:] (wave-local idx) ----
  const int b_loc = tid >> 3, dc = tid & 7;
  int idx8[8];
  {
    const int4 i0 = *(const int4*)&idxp[b_loc * 8];
    const int4 i1 = *(const int4*)&idxp[b_loc * 8 + 4];
    idx8[0] = i0.x; idx8[1] = i0.y; idx8[2] = i0.z; idx8[3] = i0.w;
    idx8[4] = i1.x; idx8[5] = i1.y; idx8[6] = i1.z; idx8[7] = i1.w;
  }
  float4 a0 = {0, 0, 0, 0}, a1 = {0, 0, 0, 0}, a2 = {0, 0, 0, 0}, a3 = {0, 0, 0, 0};
#pragma unroll
  for (int t = 0; t < 8; ++t) {
    const float4* gp = (const float4*)&ws[G_OFF + ((t * 128 + idx8[t]) << 7)];
    const float4 g0 = gp[0 * 8 + dc], g1 = gp[1 * 8 + dc];
    const float4 g2 = gp[2 * 8 + dc], g3 = gp[3 * 8 + dc];
    a0.x += g0.x; a0.y += g0.y; a0.z += g0.z; a0.w += g0.w;
    a1.x += g1.x; a1.y += g1.y; a1.z += g1.z; a1.w += g1.w;
    a2.x += g2.x; a2.y += g2.y; a2.z += g2.z; a2.w += g2.w;
    a3.x += g3.x; a3.y += g3.y; a3.z += g3.z; a3.w += g3.w;
  }
  {
    const float4* bp = (const float4*)&ws[B2_OFF];
    const float4 b0 = bp[0 * 8 + dc], b1v = bp[1 * 8 + dc];
    const float4 b2v = bp[2 * 8 + dc], b3 = bp[3 * 8 + dc];
    a0.x += b0.x; a0.y += b0.y; a0.z += b0.z; a0.w += b0.w;
    a1.x += b1v.x; a1.y += b1v.y; a1.z += b1v.z; a1.w += b1v.w;
    a2.x += b2v.x; a2.y += b2v.y; a2.z += b2v.z; a2.w += b2v.w;
    a3.x += b3.x; a3.y += b3.y; a3.z += b3.z; a3.w += b3.w;
    float4* op = (float4*)&out[(size_t)(blockIdx.x * BB + b_loc) * ZD];
    op[0 * 8 + dc] = a0; op[1 * 8 + dc] = a1; op[2 * 8 + dc] = a2; op[3 * 8 + dc] = a3;
  }

  // ---- global accumulation ----
  __syncthreads();
  if (tid == 0) atomicAdd(&ws[SQ_OFF], sqacc);
  if (tid < NE) { unsigned h = hist[tid]; if (h) atomicAdd(&((unsigned*)ws)[CT_OFF + tid], h); }
}

// ---------------------------------------------------------------------------
// fin: cmt_loss and perplexity.
// ---------------------------------------------------------------------------
__global__ __launch_bounds__(128) void fin_kernel(const float* __restrict__ ws,
                                                  float* __restrict__ out)
{
  __shared__ float red[NE];
  const int tid = threadIdx.x;
  const unsigned c = ((const unsigned*)ws)[CT_OFF + tid];
  const float cf = (float)c;
  red[tid] = cf;
  __syncthreads();
  for (int s = 64; s > 0; s >>= 1) { if (tid < s) red[tid] += red[tid + s]; __syncthreads(); }
  const float vfsum = red[0];
  __syncthreads();
  const float pr = cf / vfsum;
  red[tid] = pr * logf(pr + 1e-10f);
  __syncthreads();
  for (int s = 64; s > 0; s >>= 1) { if (tid < s) red[tid] += red[tid + s]; __syncthreads(); }
  if (tid == 0) {
    const float ent = red[0];
    const float e_latent = ws[SQ_OFF] / (vfsum * (float)NC);
    out[(size_t)BSZ * ZD + 0] = CCF * e_latent;
    out[(size_t)BSZ * ZD + 1] = expf(-ent);
  }
}

// ---------------------------------------------------------------------------
extern "C" void kernel_launch(void* const* d_in, const int* in_sizes, int n_in,
                              void* d_out, int out_size, void* d_ws, size_t ws_size,
                              hipStream_t stream)
{
  const float* fn           = (const float*)d_in[0];
  const unsigned char* mask = (const unsigned char*)d_in[1];
  const float* conv_w       = (const float*)d_in[2];
  const float* conv_b       = (const float*)d_in[3];
  const float* codebook     = (const float*)d_in[4];
  const float* fc_w         = (const float*)d_in[5];
  const float* fc_b         = (const float*)d_in[6];
  const float* mu_w         = (const float*)d_in[7];
  const float* mu_b         = (const float*)d_in[8];
  float* out = (float*)d_out;
  float* ws  = (float*)d_ws;

  hipLaunchKernelGGL(prep1_kernel, dim3(84), dim3(256), 0, stream,
                     codebook, fc_w, fc_b, mu_w, mu_b, ws);
  hipLaunchKernelGGL(prep2_kernel, dim3(1024), dim3(128), 0, stream, codebook, ws);
  hipLaunchKernelGGL(main_kernel, dim3(BSZ / BB), dim3(256), 0, stream,
                     fn, mask, conv_w, conv_b, ws, out);
  hipLaunchKernelGGL(fin_kernel, dim3(1), dim3(128), 0, stream, ws, out);
}